// Round 4
// baseline (412.427 us; speedup 1.0000x reference)
//
#include <hip/hip_runtime.h>

// Problem constants (B=4, N=512, D_in=512, D_out=256), fp32 in/out.
constexpr int Bq   = 4;
constexpr int Nq   = 512;
constexpr int DIN  = 512;
constexpr int DOUT = 256;

// ---------------------------------------------------------------------------
// K0: WT[k][o] = W[o][k]  (512x256 <- 256x512), LDS tile transpose.
// ---------------------------------------------------------------------------
__global__ __launch_bounds__(256) void k0_wt(const float* __restrict__ W,
                                             float* __restrict__ WT) {
    __shared__ float tile[32][33];
    const int k0 = blockIdx.x * 32;
    const int o0 = blockIdx.y * 32;
    const int tx = threadIdx.x;       // 32
    const int ty = threadIdx.y;       // 8
#pragma unroll
    for (int j = 0; j < 4; ++j)
        tile[ty + 8 * j][tx] = W[(o0 + ty + 8 * j) * DIN + k0 + tx];
    __syncthreads();
#pragma unroll
    for (int j = 0; j < 4; ++j)
        WT[(k0 + ty + 8 * j) * DOUT + o0 + tx] = tile[tx][ty + 8 * j];
}

// ---------------------------------------------------------------------------
// K1: Wh = H @ WT, plus WhT. Block = (b, 8 rows), 512 threads.
// H rows staged once in LDS (16 KB); WT streamed coalesced (L2-hot, identical
// for all blocks). q = t>>7 -> rows 2q,2q+1; oo = t&127 -> o-pair.
// Inner: 2 LDS broadcasts + 4 stream float2 loads + 16 FMA per 4-k group.
// ---------------------------------------------------------------------------
__global__ __launch_bounds__(512) void k1_wh(const float* __restrict__ H,
                                             const float* __restrict__ WT,
                                             float* __restrict__ Wh,
                                             float* __restrict__ WhT) {
    const int t   = threadIdx.x;
    const int blk = blockIdx.x;           // 256
    const int b   = blk >> 6;
    const int n0  = (blk & 63) << 3;
    const int q   = __builtin_amdgcn_readfirstlane(t >> 7);  // 0..3
    const int oo  = t & 127;              // o-pair
    const int r0  = 2 * q, r1 = 2 * q + 1;

    __shared__ float sH[8][512];          // 16 KB
    {
        const float4* __restrict__ g4 = (const float4*)(H + ((size_t)(b * Nq) + n0) * DIN);
        float4* s4 = (float4*)&sH[0][0];
        s4[t]       = g4[t];
        s4[t + 512] = g4[t + 512];
    }
    __syncthreads();

    const float2* __restrict__ wt2 = (const float2*)WT + oo;   // row stride 128 float2

    float2 a0 = make_float2(0.f, 0.f), a1 = make_float2(0.f, 0.f);

#pragma unroll 4
    for (int kg = 0; kg < 128; ++kg) {
        const float2 w0 = wt2[(4 * kg + 0) * 128];
        const float2 w1 = wt2[(4 * kg + 1) * 128];
        const float2 w2 = wt2[(4 * kg + 2) * 128];
        const float2 w3 = wt2[(4 * kg + 3) * 128];
        const float4 h0 = *(const float4*)&sH[r0][4 * kg];     // broadcast
        const float4 h1 = *(const float4*)&sH[r1][4 * kg];     // broadcast
        a0.x += h0.x * w0.x + h0.y * w1.x + h0.z * w2.x + h0.w * w3.x;
        a0.y += h0.x * w0.y + h0.y * w1.y + h0.z * w2.y + h0.w * w3.y;
        a1.x += h1.x * w0.x + h1.y * w1.x + h1.z * w2.x + h1.w * w3.x;
        a1.y += h1.x * w0.y + h1.y * w1.y + h1.z * w2.y + h1.w * w3.y;
    }

    ((float2*)(Wh + ((size_t)(b * Nq) + n0 + r0) * DOUT))[oo] = a0;
    ((float2*)(Wh + ((size_t)(b * Nq) + n0 + r1) * DOUT))[oo] = a1;

    float* whT = WhT + (size_t)b * DOUT * Nq;
    whT[(2 * oo + 0) * Nq + n0 + r0] = a0.x;
    whT[(2 * oo + 1) * Nq + n0 + r0] = a0.y;
    whT[(2 * oo + 0) * Nq + n0 + r1] = a1.x;
    whT[(2 * oo + 1) * Nq + n0 + r1] = a1.y;
}

// ---------------------------------------------------------------------------
// K2: e + softmax -> P.  e[i,j] = 0.6(r_i+r_j) + 0.4*sum_o a_o|Wh_i,o+Wh_j,o|
// Block = (b, 8 i-rows), 1024 threads. o staged in 8 chunks of 32 into LDS
// (64 KB); next chunk's 4 float4 loads issued before compute (latency hidden
// under 320 VALU instrs). Thread: q=t>>8 -> rows 2q,2q+1; jj=t&255 -> j-pair.
// ---------------------------------------------------------------------------
__global__ __launch_bounds__(1024) void k2_attn(const float* __restrict__ Wh,
                                                const float* __restrict__ WhT,
                                                const float* __restrict__ a,
                                                float* __restrict__ P) {
    const int t   = threadIdx.x;
    const int blk = blockIdx.x;           // 256
    const int b   = blk >> 6;
    const int i0  = (blk & 63) << 3;
    const int q   = __builtin_amdgcn_readfirstlane(t >> 8);   // 0..3
    const int jj  = t & 255;
    const int r0  = 2 * q, r1 = 2 * q + 1;

    __shared__ float sW[32][512];         // 64 KB, one o-chunk
    __shared__ float rbuf[Nq];
    __shared__ float wred[2][8][4];

    const float4* __restrict__ a4  = (const float4*)a;
    const float4* __restrict__ wi0 = (const float4*)(Wh + ((size_t)(b * Nq) + i0 + r0) * DOUT);
    const float4* __restrict__ wi1 = (const float4*)(Wh + ((size_t)(b * Nq) + i0 + r1) * DOUT);
    const float4* __restrict__ gw  = (const float4*)(WhT + (size_t)b * DOUT * Nq);

    float racc0 = 0.f, racc1 = 0.f;
    float ab00 = 0.f, ab01 = 0.f, ab10 = 0.f, ab11 = 0.f;

    float4* s4 = (float4*)&sW[0][0];

    // prologue: stage chunk 0 (o = 0..31)
    float4 st0 = gw[t], st1 = gw[t + 1024], st2 = gw[t + 2048], st3 = gw[t + 3072];
    s4[t] = st0; s4[t + 1024] = st1; s4[t + 2048] = st2; s4[t + 3072] = st3;
    __syncthreads();

    for (int c = 0; c < 8; ++c) {
        if (c < 7) {                       // issue next chunk's loads early
            const float4* __restrict__ g = gw + (size_t)(c + 1) * 4096;
            st0 = g[t]; st1 = g[t + 1024]; st2 = g[t + 2048]; st3 = g[t + 3072];
        }
#pragma unroll
        for (int oc = 0; oc < 8; ++oc) {
            const int og = c * 8 + oc;          // float4 group index over o
            const float4 av = a4[og];           // uniform
            const float4 wA = wi0[og];          // uniform
            const float4 wB = wi1[og];          // uniform
#pragma unroll
            for (int s = 0; s < 4; ++s) {
                const float aq  = ((const float*)&av)[s];
                const float wiA = ((const float*)&wA)[s];
                const float wiB = ((const float*)&wB)[s];
                const float2 wj = *(const float2*)&sW[oc * 4 + s][2 * jj];
                racc0 += aq * wj.x;
                racc1 += aq * wj.y;
                ab00 += aq * fabsf(wiA + wj.x);
                ab01 += aq * fabsf(wiA + wj.y);
                ab10 += aq * fabsf(wiB + wj.x);
                ab11 += aq * fabsf(wiB + wj.y);
            }
        }
        __syncthreads();
        if (c < 7) { s4[t] = st0; s4[t + 1024] = st1; s4[t + 2048] = st2; s4[t + 3072] = st3; }
        __syncthreads();
    }

    // publish r_j (quarter 0 covers all 512 j)
    if (q == 0) ((float2*)rbuf)[jj] = make_float2(racc0, racc1);
    __syncthreads();

    const float ri0 = rbuf[i0 + r0];
    const float ri1 = rbuf[i0 + r1];
    float e00 = 0.6f * (ri0 + racc0) + 0.4f * ab00;
    float e01 = 0.6f * (ri0 + racc1) + 0.4f * ab01;
    float e10 = 0.6f * (ri1 + racc0) + 0.4f * ab10;
    float e11 = 0.6f * (ri1 + racc1) + 0.4f * ab11;

    const int wq   = (t >> 6) & 3;
    const int lane = t & 63;

    float m0 = fmaxf(e00, e01), m1 = fmaxf(e10, e11);
#pragma unroll
    for (int off = 32; off > 0; off >>= 1) {
        m0 = fmaxf(m0, __shfl_xor(m0, off));
        m1 = fmaxf(m1, __shfl_xor(m1, off));
    }
    if (lane == 0) { wred[0][r0][wq] = m0; wred[0][r1][wq] = m1; }
    __syncthreads();
    m0 = fmaxf(fmaxf(wred[0][r0][0], wred[0][r0][1]), fmaxf(wred[0][r0][2], wred[0][r0][3]));
    m1 = fmaxf(fmaxf(wred[0][r1][0], wred[0][r1][1]), fmaxf(wred[0][r1][2], wred[0][r1][3]));

    const float p00 = __expf(e00 - m0), p01 = __expf(e01 - m0);
    const float p10 = __expf(e10 - m1), p11 = __expf(e11 - m1);
    float s0 = p00 + p01, s1 = p10 + p11;
#pragma unroll
    for (int off = 32; off > 0; off >>= 1) {
        s0 += __shfl_xor(s0, off);
        s1 += __shfl_xor(s1, off);
    }
    if (lane == 0) { wred[1][r0][wq] = s0; wred[1][r1][wq] = s1; }
    __syncthreads();
    const float inv0 = 1.0f / (wred[1][r0][0] + wred[1][r0][1] + wred[1][r0][2] + wred[1][r0][3]);
    const float inv1 = 1.0f / (wred[1][r1][0] + wred[1][r1][1] + wred[1][r1][2] + wred[1][r1][3]);

    ((float2*)(P + ((size_t)(b * Nq) + i0 + r0) * Nq))[jj] = make_float2(p00 * inv0, p01 * inv0);
    ((float2*)(P + ((size_t)(b * Nq) + i0 + r1) * Nq))[jj] = make_float2(p10 * inv1, p11 * inv1);
}

// ---------------------------------------------------------------------------
// K3: out = P @ Wh. Mirror of K1: P rows staged in LDS, Wh streamed.
// ---------------------------------------------------------------------------
__global__ __launch_bounds__(512) void k3_av(const float* __restrict__ Wh,
                                             const float* __restrict__ P,
                                             float* __restrict__ out) {
    const int t   = threadIdx.x;
    const int blk = blockIdx.x;           // 256
    const int b   = blk >> 6;
    const int i0  = (blk & 63) << 3;
    const int q   = __builtin_amdgcn_readfirstlane(t >> 7);  // 0..3
    const int oo  = t & 127;              // o-pair
    const int r0  = 2 * q, r1 = 2 * q + 1;

    __shared__ float sP[8][512];          // 16 KB
    {
        const float4* __restrict__ g4 = (const float4*)(P + ((size_t)(b * Nq) + i0) * Nq);
        float4* s4 = (float4*)&sP[0][0];
        s4[t]       = g4[t];
        s4[t + 512] = g4[t + 512];
    }
    __syncthreads();

    const float2* __restrict__ wh2 = (const float2*)(Wh + (size_t)b * Nq * DOUT) + oo;

    float2 a0 = make_float2(0.f, 0.f), a1 = make_float2(0.f, 0.f);

#pragma unroll 4
    for (int jg = 0; jg < 128; ++jg) {
        const float2 w0 = wh2[(4 * jg + 0) * 128];
        const float2 w1 = wh2[(4 * jg + 1) * 128];
        const float2 w2 = wh2[(4 * jg + 2) * 128];
        const float2 w3 = wh2[(4 * jg + 3) * 128];
        const float4 p0 = *(const float4*)&sP[r0][4 * jg];   // broadcast
        const float4 p1 = *(const float4*)&sP[r1][4 * jg];   // broadcast
        a0.x += p0.x * w0.x + p0.y * w1.x + p0.z * w2.x + p0.w * w3.x;
        a0.y += p0.x * w0.y + p0.y * w1.y + p0.z * w2.y + p0.w * w3.y;
        a1.x += p1.x * w0.x + p1.y * w1.x + p1.z * w2.x + p1.w * w3.x;
        a1.y += p1.x * w0.y + p1.y * w1.y + p1.z * w2.y + p1.w * w3.y;
    }

    ((float2*)(out + ((size_t)(b * Nq) + i0 + r0) * DOUT))[oo] = a0;
    ((float2*)(out + ((size_t)(b * Nq) + i0 + r1) * DOUT))[oo] = a1;
}

// ---------------------------------------------------------------------------
extern "C" void kernel_launch(void* const* d_in, const int* in_sizes, int n_in,
                              void* d_out, int out_size, void* d_ws, size_t ws_size,
                              hipStream_t stream) {
    const float* H = (const float*)d_in[0];   // [4,512,512]
    const float* W = (const float*)d_in[1];   // [256,512]
    const float* a = (const float*)d_in[2];   // [256,1]
    float* out = (float*)d_out;               // [4,512,256]

    float* Wh  = (float*)d_ws;                 // 2 MB
    float* WhT = Wh  + Bq * Nq * DOUT;         // 2 MB
    float* P   = WhT + Bq * Nq * DOUT;         // 4 MB
    float* WT  = P;                            // 0.5 MB, lifetime disjoint from P

    hipLaunchKernelGGL(k0_wt,   dim3(16, 8), dim3(32, 8), 0, stream, W, WT);
    hipLaunchKernelGGL(k1_wh,   dim3(256),   dim3(512),   0, stream, H, WT, Wh, WhT);
    hipLaunchKernelGGL(k2_attn, dim3(256),   dim3(1024),  0, stream, Wh, WhT, a, P);
    hipLaunchKernelGGL(k3_av,   dim3(256),   dim3(512),   0, stream, Wh, P, out);
}

// Round 5
// 171.336 us; speedup vs baseline: 2.4071x; 2.4071x over previous
//
#include <hip/hip_runtime.h>

// Problem constants (B=4, N=512, D_in=512, D_out=256), fp32 in/out.
constexpr int Bq   = 4;
constexpr int Nq   = 512;
constexpr int DIN  = 512;
constexpr int DOUT = 256;

// ---------------------------------------------------------------------------
// K0: WT[k][o] = W[o][k]  (512x256 <- 256x512), LDS tile transpose.
// ---------------------------------------------------------------------------
__global__ __launch_bounds__(256) void k0_wt(const float* __restrict__ W,
                                             float* __restrict__ WT) {
    __shared__ float tile[32][33];
    const int k0 = blockIdx.x * 32;
    const int o0 = blockIdx.y * 32;
    const int tx = threadIdx.x;       // 32
    const int ty = threadIdx.y;       // 8
#pragma unroll
    for (int j = 0; j < 4; ++j)
        tile[ty + 8 * j][tx] = W[(o0 + ty + 8 * j) * DIN + k0 + tx];
    __syncthreads();
#pragma unroll
    for (int j = 0; j < 4; ++j)
        WT[(k0 + ty + 8 * j) * DOUT + o0 + tx] = tile[tx][ty + 8 * j];
}

// ---------------------------------------------------------------------------
// K1: Wh = H @ WT (+WhT, +r = Wh.a). Block = (b, 8 n-rows), 512 threads.
// sH staged once; WT streamed in 32 double-buffered 16KB chunks (16 k-rows).
// Thread: g = t>>6 (n-row, wave-uniform), oq = t&63 (o-quad). All inner-loop
// reads are LDS (b128 canonical / broadcast). Staging = 2 float4/thread.
// ---------------------------------------------------------------------------
__global__ __launch_bounds__(512, 4) void k1_wh(const float* __restrict__ H,
                                                const float* __restrict__ WT,
                                                const float* __restrict__ a,
                                                float* __restrict__ Wh,
                                                float* __restrict__ WhT,
                                                float* __restrict__ r) {
    const int t   = threadIdx.x;
    const int blk = blockIdx.x;           // 256
    const int b   = blk & 3;              // XCD-swizzled batch
    const int n0  = (blk >> 2) << 3;
    const int g   = t >> 6;               // n-row (wave-uniform)
    const int oq  = t & 63;               // o-quad

    __shared__ float sH[8 * 512];         // 16 KB
    __shared__ float sW[2][16 * 256];     // 2 x 16 KB

    {   // stage H rows (once) + chunk 0
        const float4* src = (const float4*)(H + ((size_t)b * Nq + n0) * DIN);
        float4* dst = (float4*)sH;
        dst[t] = src[t]; dst[t + 512] = src[t + 512];
        const float4* ws = (const float4*)WT;
        float4* wd = (float4*)sW[0];
        wd[t] = ws[t]; wd[t + 512] = ws[t + 512];
    }
    __syncthreads();

    float4 acc = make_float4(0.f, 0.f, 0.f, 0.f);

    for (int c = 0; c < 32; ++c) {
        const int cn = (c + 1) & 31;               // wrap: last prefetch harmless
        const float4* src = (const float4*)WT + (size_t)cn * 1024;
        const float4 p0 = src[t], p1 = src[t + 512];

        const float* w    = sW[c & 1];
        const float* hrow = sH + g * 512 + c * 16;
#pragma unroll
        for (int kq = 0; kq < 4; ++kq) {
            const float4 h4 = *(const float4*)(hrow + 4 * kq);   // broadcast
#pragma unroll
            for (int kk = 0; kk < 4; ++kk) {
                const float4 w4 = *(const float4*)(w + (4 * kq + kk) * 256 + 4 * oq);
                const float hk = ((const float*)&h4)[kk];
                acc.x += hk * w4.x; acc.y += hk * w4.y;
                acc.z += hk * w4.z; acc.w += hk * w4.w;
            }
        }
        __syncthreads();
        float4* dst = (float4*)sW[cn & 1];
        dst[t] = p0; dst[t + 512] = p1;
        __syncthreads();
    }

    // Wh (coalesced float4)
    ((float4*)(Wh + ((size_t)b * Nq + n0 + g) * DOUT))[oq] = acc;

    // WhT[b][o][n]
    float* wT = WhT + (size_t)b * DOUT * Nq;
    wT[(4 * oq + 0) * Nq + n0 + g] = acc.x;
    wT[(4 * oq + 1) * Nq + n0 + g] = acc.y;
    wT[(4 * oq + 2) * Nq + n0 + g] = acc.z;
    wT[(4 * oq + 3) * Nq + n0 + g] = acc.w;

    // r[b][n] = a . Wh[b][n]  (wave owns one row)
    const float4 a4 = ((const float4*)a)[oq];
    float rp = a4.x * acc.x + a4.y * acc.y + a4.z * acc.z + a4.w * acc.w;
#pragma unroll
    for (int off = 32; off > 0; off >>= 1) rp += __shfl_xor(rp, off);
    if ((t & 63) == 0) r[(size_t)b * Nq + n0 + g] = rp;
}

// ---------------------------------------------------------------------------
// K2: e + softmax -> P.  e[i,j] = 0.6(r_i+r_j) + 0.4*sum_o a_o|Wh_io + Wh_jo|
// Block = (b, 8 i-rows), 512 threads. WhT streamed in 16 double-buffered
// 32KB chunks (16 o-rows x 512 j). Thread: q = t>>7 -> rows 2q,2q+1
// (wave-uniform); jj = t&127 -> j-quad. Uniforms (a, Wh_i, r) read from LDS
// as broadcasts -- NO register arrays (R4 spill lesson).
// ---------------------------------------------------------------------------
__global__ __launch_bounds__(512, 4) void k2_attn(const float* __restrict__ Wh,
                                                  const float* __restrict__ WhT,
                                                  const float* __restrict__ a,
                                                  const float* __restrict__ r,
                                                  float* __restrict__ P) {
    const int t   = threadIdx.x;
    const int blk = blockIdx.x;           // 256
    const int b   = blk & 3;
    const int i0  = (blk >> 2) << 3;
    const int q   = t >> 7;               // 0..3 (wave-uniform)
    const int jj  = t & 127;              // j-quad
    const int r0  = 2 * q, r1 = 2 * q + 1;

    __shared__ float sW[2][16 * 512];     // 2 x 32 KB
    __shared__ float sI[8 * 256];         // 8 KB  (Wh i-rows)
    __shared__ float sR[512];             // 2 KB  (r[b][:])
    __shared__ float sA[256];             // 1 KB
    __shared__ float wred[2][8][2];

    const float4* gW = (const float4*)(WhT + (size_t)b * DOUT * Nq);

    {   // one-time stages
        ((float4*)sI)[t] = ((const float4*)(Wh + ((size_t)b * Nq + i0) * DOUT))[t];
        if (t < 128) ((float4*)sR)[t] = ((const float4*)(r + (size_t)b * Nq))[t];
        else if (t < 192) ((float4*)sA)[t - 128] = ((const float4*)a)[t - 128];
        // chunk 0
        float4* dst = (float4*)sW[0];
        dst[t] = gW[t]; dst[t + 512] = gW[t + 512];
        dst[t + 1024] = gW[t + 1024]; dst[t + 1536] = gW[t + 1536];
    }
    __syncthreads();

    float ab0[4] = {0.f, 0.f, 0.f, 0.f};
    float ab1[4] = {0.f, 0.f, 0.f, 0.f};

    for (int c = 0; c < 16; ++c) {
        const int cn = (c + 1) & 15;
        const float4* src = gW + (size_t)cn * 2048;
        const float4 p0 = src[t], p1 = src[t + 512], p2 = src[t + 1024], p3 = src[t + 1536];

        const float* w = sW[c & 1];
#pragma unroll
        for (int og = 0; og < 4; ++og) {
            const int ob = c * 16 + og * 4;                       // global o base
            const float4 a4  = *(const float4*)(sA + ob);         // broadcast
            const float4 wA4 = *(const float4*)(sI + r0 * 256 + ob);
            const float4 wB4 = *(const float4*)(sI + r1 * 256 + ob);
#pragma unroll
            for (int s = 0; s < 4; ++s) {
                const int ol = og * 4 + s;                        // o within chunk
                const float4 wj = *(const float4*)(w + ol * 512 + 4 * jj);
                const float aq  = ((const float*)&a4)[s];
                const float wiA = ((const float*)&wA4)[s];
                const float wiB = ((const float*)&wB4)[s];
#pragma unroll
                for (int x = 0; x < 4; ++x) {
                    const float wjx = ((const float*)&wj)[x];
                    ab0[x] += aq * fabsf(wiA + wjx);
                    ab1[x] += aq * fabsf(wiB + wjx);
                }
            }
        }
        __syncthreads();
        float4* dst = (float4*)sW[cn & 1];
        dst[t] = p0; dst[t + 512] = p1; dst[t + 1024] = p2; dst[t + 1536] = p3;
        __syncthreads();
    }

    // e = 0.6(ri + rj) + 0.4*ab
    const float ri0 = sR[i0 + r0], ri1 = sR[i0 + r1];
    const float4 rj4 = *(const float4*)(sR + 4 * jj);
    float e0[4], e1[4];
#pragma unroll
    for (int x = 0; x < 4; ++x) {
        const float rj = ((const float*)&rj4)[x];
        e0[x] = 0.6f * (ri0 + rj) + 0.4f * ab0[x];
        e1[x] = 0.6f * (ri1 + rj) + 0.4f * ab1[x];
    }

    const int w2   = (t >> 6) & 1;     // wave within row-group
    const int lane = t & 63;

    float m0 = fmaxf(fmaxf(e0[0], e0[1]), fmaxf(e0[2], e0[3]));
    float m1 = fmaxf(fmaxf(e1[0], e1[1]), fmaxf(e1[2], e1[3]));
#pragma unroll
    for (int off = 32; off > 0; off >>= 1) {
        m0 = fmaxf(m0, __shfl_xor(m0, off));
        m1 = fmaxf(m1, __shfl_xor(m1, off));
    }
    if (lane == 0) { wred[0][r0][w2] = m0; wred[0][r1][w2] = m1; }
    __syncthreads();
    m0 = fmaxf(wred[0][r0][0], wred[0][r0][1]);
    m1 = fmaxf(wred[0][r1][0], wred[0][r1][1]);

    float pv0[4], pv1[4];
    float s0 = 0.f, s1 = 0.f;
#pragma unroll
    for (int x = 0; x < 4; ++x) {
        pv0[x] = __expf(e0[x] - m0); s0 += pv0[x];
        pv1[x] = __expf(e1[x] - m1); s1 += pv1[x];
    }
#pragma unroll
    for (int off = 32; off > 0; off >>= 1) {
        s0 += __shfl_xor(s0, off);
        s1 += __shfl_xor(s1, off);
    }
    if (lane == 0) { wred[1][r0][w2] = s0; wred[1][r1][w2] = s1; }
    __syncthreads();
    const float inv0 = 1.0f / (wred[1][r0][0] + wred[1][r0][1]);
    const float inv1 = 1.0f / (wred[1][r1][0] + wred[1][r1][1]);

    ((float4*)(P + ((size_t)b * Nq + i0 + r0) * Nq))[jj] =
        make_float4(pv0[0] * inv0, pv0[1] * inv0, pv0[2] * inv0, pv0[3] * inv0);
    ((float4*)(P + ((size_t)b * Nq + i0 + r1) * Nq))[jj] =
        make_float4(pv1[0] * inv1, pv1[1] * inv1, pv1[2] * inv1, pv1[3] * inv1);
}

// ---------------------------------------------------------------------------
// K3: out = P @ Wh. Block = (b, 8 i-rows), 512 threads. sP staged once;
// Wh streamed in 32 double-buffered 16KB chunks (16 j-rows x 256 o).
// Thread: g = t>>6 (i-row, wave-uniform), oq = t&63 (o-quad).
// ---------------------------------------------------------------------------
__global__ __launch_bounds__(512, 4) void k3_av(const float* __restrict__ Wh,
                                                const float* __restrict__ P,
                                                float* __restrict__ out) {
    const int t   = threadIdx.x;
    const int blk = blockIdx.x;           // 256
    const int b   = blk & 3;
    const int i0  = (blk >> 2) << 3;
    const int g   = t >> 6;               // i-row (wave-uniform)
    const int oq  = t & 63;               // o-quad

    __shared__ float sP[8 * 512];         // 16 KB
    __shared__ float sW[2][16 * 256];     // 2 x 16 KB

    const float4* gW = (const float4*)(Wh + (size_t)b * Nq * DOUT);

    {   // stage P rows + chunk 0
        const float4* src = (const float4*)(P + ((size_t)b * Nq + i0) * Nq);
        float4* dst = (float4*)sP;
        dst[t] = src[t]; dst[t + 512] = src[t + 512];
        float4* wd = (float4*)sW[0];
        wd[t] = gW[t]; wd[t + 512] = gW[t + 512];
    }
    __syncthreads();

    float4 acc = make_float4(0.f, 0.f, 0.f, 0.f);

    for (int c = 0; c < 32; ++c) {
        const int cn = (c + 1) & 31;
        const float4* src = gW + (size_t)cn * 1024;
        const float4 p0 = src[t], p1 = src[t + 512];

        const float* w    = sW[c & 1];
        const float* prow = sP + g * 512 + c * 16;
#pragma unroll
        for (int jq = 0; jq < 4; ++jq) {
            const float4 pj4 = *(const float4*)(prow + 4 * jq);   // broadcast
#pragma unroll
            for (int jx = 0; jx < 4; ++jx) {
                const float4 w4 = *(const float4*)(w + (4 * jq + jx) * 256 + 4 * oq);
                const float pj = ((const float*)&pj4)[jx];
                acc.x += pj * w4.x; acc.y += pj * w4.y;
                acc.z += pj * w4.z; acc.w += pj * w4.w;
            }
        }
        __syncthreads();
        float4* dst = (float4*)sW[cn & 1];
        dst[t] = p0; dst[t + 512] = p1;
        __syncthreads();
    }

    ((float4*)(out + ((size_t)b * Nq + i0 + g) * DOUT))[oq] = acc;
}

// ---------------------------------------------------------------------------
extern "C" void kernel_launch(void* const* d_in, const int* in_sizes, int n_in,
                              void* d_out, int out_size, void* d_ws, size_t ws_size,
                              hipStream_t stream) {
    const float* H = (const float*)d_in[0];   // [4,512,512]
    const float* W = (const float*)d_in[1];   // [256,512]
    const float* a = (const float*)d_in[2];   // [256,1]
    float* out = (float*)d_out;               // [4,512,256]

    float* Wh  = (float*)d_ws;                 // 2 MB
    float* WhT = Wh  + Bq * Nq * DOUT;         // 2 MB
    float* P   = WhT + Bq * Nq * DOUT;         // 4 MB
    float* WT  = P;                            // 0.5 MB, dead before K2 writes P
    float* r   = out;                          // 8 KB stash in d_out; K2 reads it
                                               // before K3 overwrites all of out

    hipLaunchKernelGGL(k0_wt,   dim3(16, 8), dim3(32, 8), 0, stream, W, WT);
    hipLaunchKernelGGL(k1_wh,   dim3(256),   dim3(512),   0, stream, H, WT, a, Wh, WhT, r);
    hipLaunchKernelGGL(k2_attn, dim3(256),   dim3(512),   0, stream, Wh, WhT, a, r, P);
    hipLaunchKernelGGL(k3_av,   dim3(256),   dim3(512),   0, stream, Wh, P, out);
}

// Round 6
// 165.025 us; speedup vs baseline: 2.4992x; 1.0382x over previous
//
#include <hip/hip_runtime.h>

// Problem constants (B=4, N=512, D_in=512, D_out=256), fp32 in/out.
constexpr int Bq   = 4;
constexpr int Nq   = 512;
constexpr int DIN  = 512;
constexpr int DOUT = 256;

__device__ __forceinline__ void fma4(float4& acc, const float s, const float4 v) {
    acc.x += s * v.x; acc.y += s * v.y; acc.z += s * v.z; acc.w += s * v.w;
}

// ---------------------------------------------------------------------------
// K0: WT[k][o] = W[o][k]  (512x256 <- 256x512), LDS tile transpose.
// ---------------------------------------------------------------------------
__global__ __launch_bounds__(256) void k0_wt(const float* __restrict__ W,
                                             float* __restrict__ WT) {
    __shared__ float tile[32][33];
    const int k0 = blockIdx.x * 32;
    const int o0 = blockIdx.y * 32;
    const int tx = threadIdx.x;       // 32
    const int ty = threadIdx.y;       // 8
#pragma unroll
    for (int j = 0; j < 4; ++j)
        tile[ty + 8 * j][tx] = W[(o0 + ty + 8 * j) * DIN + k0 + tx];
    __syncthreads();
#pragma unroll
    for (int j = 0; j < 4; ++j)
        WT[(k0 + ty + 8 * j) * DOUT + o0 + tx] = tile[tx][ty + 8 * j];
}

// ---------------------------------------------------------------------------
// K1: Wh = H @ WT (+ WhT + r = Wh.a). Block = (b, 8 n-rows), 512 threads.
// NO LDS. H row = wave-uniform -> s_load. WT stream = coalesced float4
// (wave reads a full 1KB WT row), register double-buffered 8 deep.
// Thread: g = wave (n-row), oq = t&63 (o-quad). 2048 fma/thread.
// ---------------------------------------------------------------------------
__global__ __launch_bounds__(512, 2) void k1_wh(const float* __restrict__ H,
                                                const float* __restrict__ WT,
                                                const float* __restrict__ a,
                                                float* __restrict__ Wh,
                                                float* __restrict__ WhT,
                                                float* __restrict__ r) {
    const int t   = threadIdx.x;
    const int blk = blockIdx.x;           // 256
    const int b   = blk & 3;              // XCD-swizzled batch
    const int n0  = (blk >> 2) << 3;
    const int g   = __builtin_amdgcn_readfirstlane(t >> 6);  // n-row (wave idx)
    const int oq  = t & 63;               // o-quad

    const float* __restrict__ hrow = H + ((size_t)(b * Nq) + n0 + g) * DIN;  // uniform
    const float4* __restrict__ wt4 = (const float4*)WT + oq;                 // [k]*64

    float4 acc = make_float4(0.f, 0.f, 0.f, 0.f);
    float4 bufA[8], bufB[8];

#pragma unroll
    for (int s = 0; s < 8; ++s) bufA[s] = wt4[s * 64];

    for (int cc = 0; cc < 32; ++cc) {     // 16 k per cc
        const int kA = cc * 16, kB = kA + 8;
#pragma unroll
        for (int s = 0; s < 8; ++s) bufB[s] = wt4[(kB + s) * 64];
        {
            const float4 h0 = *(const float4*)(hrow + kA);      // s_load
            const float4 h1 = *(const float4*)(hrow + kA + 4);  // s_load
            fma4(acc, h0.x, bufA[0]); fma4(acc, h0.y, bufA[1]);
            fma4(acc, h0.z, bufA[2]); fma4(acc, h0.w, bufA[3]);
            fma4(acc, h1.x, bufA[4]); fma4(acc, h1.y, bufA[5]);
            fma4(acc, h1.z, bufA[6]); fma4(acc, h1.w, bufA[7]);
        }
        if (cc < 31) {
#pragma unroll
            for (int s = 0; s < 8; ++s) bufA[s] = wt4[(kA + 16 + s) * 64];
        }
        {
            const float4 h0 = *(const float4*)(hrow + kB);      // s_load
            const float4 h1 = *(const float4*)(hrow + kB + 4);  // s_load
            fma4(acc, h0.x, bufB[0]); fma4(acc, h0.y, bufB[1]);
            fma4(acc, h0.z, bufB[2]); fma4(acc, h0.w, bufB[3]);
            fma4(acc, h1.x, bufB[4]); fma4(acc, h1.y, bufB[5]);
            fma4(acc, h1.z, bufB[6]); fma4(acc, h1.w, bufB[7]);
        }
    }

    // Wh: coalesced float4
    ((float4*)(Wh + ((size_t)(b * Nq) + n0 + g) * DOUT))[oq] = acc;

    // WhT[b][o][n0+g] (scattered dwords; L2-absorbed)
    float* wT = WhT + (size_t)b * DOUT * Nq;
    wT[(4 * oq + 0) * Nq + n0 + g] = acc.x;
    wT[(4 * oq + 1) * Nq + n0 + g] = acc.y;
    wT[(4 * oq + 2) * Nq + n0 + g] = acc.z;
    wT[(4 * oq + 3) * Nq + n0 + g] = acc.w;

    // r[b][n] = a . Wh[b][n]  (wave covers all 256 o of its row)
    const float4 a4 = ((const float4*)a)[oq];                   // s_load? per-lane -> vector; fine
    float rp = a4.x * acc.x + a4.y * acc.y + a4.z * acc.z + a4.w * acc.w;
#pragma unroll
    for (int off = 32; off > 0; off >>= 1) rp += __shfl_xor(rp, off);
    if ((t & 63) == 0) r[(size_t)b * Nq + n0 + g] = rp;
}

// ---------------------------------------------------------------------------
// K2: e + softmax -> P.  e[i,j] = 0.6(r_i+r_j) + 0.4*sum_o a_o|Wh_io + Wh_jo|
// Block = (b, 8 i-rows), 512 threads, thread = column j = t. NO LDS staging.
// a / Wh_i / r_i are block-uniform -> s_load. WhT column stream: coalesced
// dword per o, register double-buffered 16 deep. ab[8] accumulators:
// 16 VALU per load. Softmax: wave butterfly + tiny LDS cross-wave.
// ---------------------------------------------------------------------------
__global__ __launch_bounds__(512, 2) void k2_attn(const float* __restrict__ Wh,
                                                  const float* __restrict__ WhT,
                                                  const float* __restrict__ a,
                                                  const float* __restrict__ r,
                                                  float* __restrict__ P) {
    const int t   = threadIdx.x;          // j column
    const int blk = blockIdx.x;           // 256
    const int b   = blk & 3;
    const int i0  = (blk >> 2) << 3;

    const float* __restrict__ wj  = WhT + (size_t)b * DOUT * Nq + t;   // + o*Nq
    const float* __restrict__ gwi = Wh + ((size_t)b * Nq + i0) * DOUT; // uniform
    const float* __restrict__ gr  = r + (size_t)b * Nq;

    float ab[8] = {0.f, 0.f, 0.f, 0.f, 0.f, 0.f, 0.f, 0.f};
    float bufA[16], bufB[16];

#pragma unroll
    for (int s = 0; s < 16; ++s) bufA[s] = wj[s * Nq];

    for (int cc = 0; cc < 8; ++cc) {      // 32 o per cc
        const int oA = cc * 32, oB = oA + 16;
#pragma unroll
        for (int s = 0; s < 16; ++s) bufB[s] = wj[(oB + s) * Nq];
#pragma unroll
        for (int grp = 0; grp < 4; ++grp) {
            const int o4 = oA + grp * 4;
            const float4 a4 = *(const float4*)(a + o4);                 // s_load
#pragma unroll
            for (int rr = 0; rr < 8; ++rr) {
                const float4 wi4 = *(const float4*)(gwi + rr * DOUT + o4); // s_load
#pragma unroll
                for (int s2 = 0; s2 < 4; ++s2) {
                    const float aq = ((const float*)&a4)[s2];
                    const float wi = ((const float*)&wi4)[s2];
                    ab[rr] += aq * fabsf(wi + bufA[grp * 4 + s2]);
                }
            }
        }
        if (cc < 7) {
#pragma unroll
            for (int s = 0; s < 16; ++s) bufA[s] = wj[(oA + 32 + s) * Nq];
        }
#pragma unroll
        for (int grp = 0; grp < 4; ++grp) {
            const int o4 = oB + grp * 4;
            const float4 a4 = *(const float4*)(a + o4);                 // s_load
#pragma unroll
            for (int rr = 0; rr < 8; ++rr) {
                const float4 wi4 = *(const float4*)(gwi + rr * DOUT + o4); // s_load
#pragma unroll
                for (int s2 = 0; s2 < 4; ++s2) {
                    const float aq = ((const float*)&a4)[s2];
                    const float wi = ((const float*)&wi4)[s2];
                    ab[rr] += aq * fabsf(wi + bufB[grp * 4 + s2]);
                }
            }
        }
    }

    // e[rr] = 0.6*(r_i + r_j) + 0.4*ab
    const float rj = gr[t];               // coalesced
    float e[8];
#pragma unroll
    for (int rr = 0; rr < 8; ++rr)
        e[rr] = 0.6f * (gr[i0 + rr] + rj) + 0.4f * ab[rr];   // gr[i0+rr] = s_load

    __shared__ float wred[2][8][8];       // [max/sum][row][wave]
    const int lane = t & 63;
    const int w    = t >> 6;

#pragma unroll
    for (int rr = 0; rr < 8; ++rr) {
        float v = e[rr];
#pragma unroll
        for (int off = 32; off > 0; off >>= 1) v = fmaxf(v, __shfl_xor(v, off));
        if (lane == 0) wred[0][rr][w] = v;
    }
    __syncthreads();

    float p[8];
    float4 q0, q1;
#pragma unroll
    for (int rr = 0; rr < 8; ++rr) {
        q0 = *(const float4*)&wred[0][rr][0];
        q1 = *(const float4*)&wred[0][rr][4];
        const float m = fmaxf(fmaxf(fmaxf(q0.x, q0.y), fmaxf(q0.z, q0.w)),
                              fmaxf(fmaxf(q1.x, q1.y), fmaxf(q1.z, q1.w)));
        p[rr] = __expf(e[rr] - m);
    }
#pragma unroll
    for (int rr = 0; rr < 8; ++rr) {
        float v = p[rr];
#pragma unroll
        for (int off = 32; off > 0; off >>= 1) v += __shfl_xor(v, off);
        if (lane == 0) wred[1][rr][w] = v;
    }
    __syncthreads();

    float* prow = P + ((size_t)b * Nq + i0) * Nq + t;
#pragma unroll
    for (int rr = 0; rr < 8; ++rr) {
        q0 = *(const float4*)&wred[1][rr][0];
        q1 = *(const float4*)&wred[1][rr][4];
        const float s = (q0.x + q0.y + q0.z + q0.w) + (q1.x + q1.y + q1.z + q1.w);
        prow[rr * Nq] = p[rr] * (1.0f / s);   // coalesced
    }
}

// ---------------------------------------------------------------------------
// K3: out = P @ Wh. Mirror of K1. Block = (b, 8 i-rows), 512 threads.
// P row = wave-uniform -> s_load; Wh stream coalesced float4, dbuf 8 deep.
// ---------------------------------------------------------------------------
__global__ __launch_bounds__(512, 2) void k3_av(const float* __restrict__ Wh,
                                                const float* __restrict__ P,
                                                float* __restrict__ out) {
    const int t   = threadIdx.x;
    const int blk = blockIdx.x;           // 256
    const int b   = blk & 3;
    const int i0  = (blk >> 2) << 3;
    const int g   = __builtin_amdgcn_readfirstlane(t >> 6);  // i-row (wave idx)
    const int oq  = t & 63;               // o-quad

    const float* __restrict__ prow = P + ((size_t)(b * Nq) + i0 + g) * Nq;  // uniform
    const float4* __restrict__ wh4 = (const float4*)(Wh + (size_t)b * Nq * DOUT) + oq;

    float4 acc = make_float4(0.f, 0.f, 0.f, 0.f);
    float4 bufA[8], bufB[8];

#pragma unroll
    for (int s = 0; s < 8; ++s) bufA[s] = wh4[s * 64];

    for (int cc = 0; cc < 32; ++cc) {     // 16 j per cc
        const int jA = cc * 16, jB = jA + 8;
#pragma unroll
        for (int s = 0; s < 8; ++s) bufB[s] = wh4[(jB + s) * 64];
        {
            const float4 p0 = *(const float4*)(prow + jA);      // s_load
            const float4 p1 = *(const float4*)(prow + jA + 4);  // s_load
            fma4(acc, p0.x, bufA[0]); fma4(acc, p0.y, bufA[1]);
            fma4(acc, p0.z, bufA[2]); fma4(acc, p0.w, bufA[3]);
            fma4(acc, p1.x, bufA[4]); fma4(acc, p1.y, bufA[5]);
            fma4(acc, p1.z, bufA[6]); fma4(acc, p1.w, bufA[7]);
        }
        if (cc < 31) {
#pragma unroll
            for (int s = 0; s < 8; ++s) bufA[s] = wh4[(jA + 16 + s) * 64];
        }
        {
            const float4 p0 = *(const float4*)(prow + jB);      // s_load
            const float4 p1 = *(const float4*)(prow + jB + 4);  // s_load
            fma4(acc, p0.x, bufB[0]); fma4(acc, p0.y, bufB[1]);
            fma4(acc, p0.z, bufB[2]); fma4(acc, p0.w, bufB[3]);
            fma4(acc, p1.x, bufB[4]); fma4(acc, p1.y, bufB[5]);
            fma4(acc, p1.z, bufB[6]); fma4(acc, p1.w, bufB[7]);
        }
    }

    ((float4*)(out + ((size_t)(b * Nq) + i0 + g) * DOUT))[oq] = acc;
}

// ---------------------------------------------------------------------------
extern "C" void kernel_launch(void* const* d_in, const int* in_sizes, int n_in,
                              void* d_out, int out_size, void* d_ws, size_t ws_size,
                              hipStream_t stream) {
    const float* H = (const float*)d_in[0];   // [4,512,512]
    const float* W = (const float*)d_in[1];   // [256,512]
    const float* a = (const float*)d_in[2];   // [256,1]
    float* out = (float*)d_out;               // [4,512,256]

    float* Wh  = (float*)d_ws;                 // 2 MB
    float* WhT = Wh  + Bq * Nq * DOUT;         // 2 MB
    float* P   = WhT + Bq * Nq * DOUT;         // 4 MB
    float* WT  = P;                            // 0.5 MB, dead before K2 writes P
    float* r   = out;                          // 8 KB stash in d_out; K2 reads it
                                               // before K3 overwrites all of out

    hipLaunchKernelGGL(k0_wt,   dim3(16, 8), dim3(32, 8), 0, stream, W, WT);
    hipLaunchKernelGGL(k1_wh,   dim3(256),   dim3(512),   0, stream, H, WT, a, Wh, WhT, r);
    hipLaunchKernelGGL(k2_attn, dim3(256),   dim3(512),   0, stream, Wh, WhT, a, r, P);
    hipLaunchKernelGGL(k3_av,   dim3(256),   dim3(512),   0, stream, Wh, P, out);
}

// Round 7
// 122.141 us; speedup vs baseline: 3.3766x; 1.3511x over previous
//
#include <hip/hip_runtime.h>

// Problem constants (B=4, N=512, D_in=512, D_out=256), fp32 in/out.
constexpr int Bq   = 4;
constexpr int Nq   = 512;
constexpr int DIN  = 512;
constexpr int DOUT = 256;

__device__ __forceinline__ void fma4(float4& acc, const float s, const float4 v) {
    acc.x = __builtin_fmaf(s, v.x, acc.x);
    acc.y = __builtin_fmaf(s, v.y, acc.y);
    acc.z = __builtin_fmaf(s, v.z, acc.z);
    acc.w = __builtin_fmaf(s, v.w, acc.w);
}

// ---------------------------------------------------------------------------
// K0: WT[k][o] = W[o][k]  (512x256 <- 256x512), LDS tile transpose.
// ---------------------------------------------------------------------------
__global__ __launch_bounds__(256) void k0_wt(const float* __restrict__ W,
                                             float* __restrict__ WT) {
    __shared__ float tile[32][33];
    const int k0 = blockIdx.x * 32;
    const int o0 = blockIdx.y * 32;
    const int tx = threadIdx.x;       // 32
    const int ty = threadIdx.y;       // 8
#pragma unroll
    for (int j = 0; j < 4; ++j)
        tile[ty + 8 * j][tx] = W[(o0 + ty + 8 * j) * DIN + k0 + tx];
    __syncthreads();
#pragma unroll
    for (int j = 0; j < 4; ++j)
        WT[(k0 + ty + 8 * j) * DOUT + o0 + tx] = tile[tx][ty + 8 * j];
}

// ---------------------------------------------------------------------------
// K1: Wh = H @ WT (+ WhT + r = Wh.a). Block = (b, 8 n-rows), 512 threads.
// Thread = (k-phase p = wave, o-quad oq). Each WT float4 is loaded ONCE and
// used for all 8 rows (8 float4 accs in registers) -> block stream = 512 KB,
// no redundancy. H rows wave-uniform -> s_load. Phase partials reduced via
// 64 KB LDS, one barrier.
// ---------------------------------------------------------------------------
__global__ __launch_bounds__(512, 2) void k1_wh(const float* __restrict__ H,
                                                const float* __restrict__ WT,
                                                const float* __restrict__ a,
                                                float* __restrict__ Wh,
                                                float* __restrict__ WhT,
                                                float* __restrict__ r) {
    const int t   = threadIdx.x;
    const int blk = blockIdx.x;           // 256
    const int b   = blk & 3;              // XCD-swizzled batch
    const int n0  = (blk >> 2) << 3;
    const int p   = __builtin_amdgcn_readfirstlane(t >> 6);  // k-phase 0..7
    const int oq  = t & 63;               // o-quad

    const float* __restrict__ hbase = H + ((size_t)(b * Nq) + n0) * DIN;  // + row*DIN
    const float4* __restrict__ wt4  = (const float4*)WT + oq;             // [k]*64

    float4 acc[8];
#pragma unroll
    for (int rr = 0; rr < 8; ++rr) acc[rr] = make_float4(0.f, 0.f, 0.f, 0.f);

    const int k0 = p * 64;                // this phase's 64-k chunk
    float4 bufA[4], bufB[4];
#pragma unroll
    for (int s = 0; s < 4; ++s) bufA[s] = wt4[(k0 + s) * 64];

    for (int it = 0; it < 8; ++it) {      // 8 k per it
        const int kA = k0 + it * 8, kB = kA + 4;
#pragma unroll
        for (int s = 0; s < 4; ++s) bufB[s] = wt4[(kB + s) * 64];
#pragma unroll
        for (int rr = 0; rr < 8; ++rr) {
            const float4 h4 = *(const float4*)(hbase + rr * DIN + kA);   // s_load
            fma4(acc[rr], h4.x, bufA[0]); fma4(acc[rr], h4.y, bufA[1]);
            fma4(acc[rr], h4.z, bufA[2]); fma4(acc[rr], h4.w, bufA[3]);
        }
        if (it < 7) {
#pragma unroll
            for (int s = 0; s < 4; ++s) bufA[s] = wt4[(kA + 8 + s) * 64];
        }
#pragma unroll
        for (int rr = 0; rr < 8; ++rr) {
            const float4 h4 = *(const float4*)(hbase + rr * DIN + kB);   // s_load
            fma4(acc[rr], h4.x, bufB[0]); fma4(acc[rr], h4.y, bufB[1]);
            fma4(acc[rr], h4.z, bufB[2]); fma4(acc[rr], h4.w, bufB[3]);
        }
    }

    __shared__ float4 sPart[8][8][64];    // [phase][row][oq] = 64 KB
#pragma unroll
    for (int rr = 0; rr < 8; ++rr) sPart[p][rr][oq] = acc[rr];
    __syncthreads();

    const int g = p;                       // final pass: wave = row
    float4 fin = make_float4(0.f, 0.f, 0.f, 0.f);
#pragma unroll
    for (int pp = 0; pp < 8; ++pp) {
        const float4 v = sPart[pp][g][oq];
        fin.x += v.x; fin.y += v.y; fin.z += v.z; fin.w += v.w;
    }

    // Wh: coalesced float4
    ((float4*)(Wh + ((size_t)(b * Nq) + n0 + g) * DOUT))[oq] = fin;

    // WhT[b][o][n0+g]
    float* wT = WhT + (size_t)b * DOUT * Nq;
    wT[(4 * oq + 0) * Nq + n0 + g] = fin.x;
    wT[(4 * oq + 1) * Nq + n0 + g] = fin.y;
    wT[(4 * oq + 2) * Nq + n0 + g] = fin.z;
    wT[(4 * oq + 3) * Nq + n0 + g] = fin.w;

    // r[b][n] = a . Wh[b][n]  (wave covers all 256 o of its row)
    const float4 a4 = ((const float4*)a)[oq];
    float rp = a4.x * fin.x + a4.y * fin.y + a4.z * fin.z + a4.w * fin.w;
#pragma unroll
    for (int off = 32; off > 0; off >>= 1) rp += __shfl_xor(rp, off);
    if ((t & 63) == 0) r[(size_t)b * Nq + n0 + g] = rp;
}

// ---------------------------------------------------------------------------
// K2: e + softmax -> P.  e[i,j] = 0.6(r_i+r_j) + 0.4*sum_o a_o|Wh_io + Wh_jo|
// Block = (b, 8 i-rows), 1024 threads (16 waves -> 4 waves/SIMD).
// half = t>>9 (scalar) owns o-range [128*half, 128*half+128); j = t&511.
// Stream: WhT column dwords, 16-deep double-buffered. Uniforms via s_load.
// abs folded via __builtin_fmaf(aq, fabsf(x), acc). Halves combined in LDS.
// ---------------------------------------------------------------------------
__global__ __launch_bounds__(1024, 4) void k2_attn(const float* __restrict__ Wh,
                                                   const float* __restrict__ WhT,
                                                   const float* __restrict__ a,
                                                   const float* __restrict__ r,
                                                   float* __restrict__ P) {
    const int t    = threadIdx.x;
    const int blk  = blockIdx.x;          // 256
    const int b    = blk & 3;
    const int i0   = (blk >> 2) << 3;
    const int half = __builtin_amdgcn_readfirstlane(t >> 9);  // 0/1, scalar
    const int j    = t & 511;
    const int obase = half * 128;

    const float* __restrict__ wj  = WhT + (size_t)b * DOUT * Nq + (size_t)obase * Nq + j;
    const float* __restrict__ gwi = Wh + ((size_t)b * Nq + i0) * DOUT + obase;  // uniform
    const float* __restrict__ ga  = a + obase;                                   // uniform
    const float* __restrict__ gr  = r + (size_t)b * Nq;

    float ab[8] = {0.f, 0.f, 0.f, 0.f, 0.f, 0.f, 0.f, 0.f};
    float bufA[16], bufB[16];

#pragma unroll
    for (int s = 0; s < 16; ++s) bufA[s] = wj[s * Nq];

    for (int cc = 0; cc < 4; ++cc) {      // 32 o per cc (this half: 128 o)
        const int oA = cc * 32, oB = oA + 16;
#pragma unroll
        for (int s = 0; s < 16; ++s) bufB[s] = wj[(oB + s) * Nq];
#pragma unroll
        for (int grp = 0; grp < 4; ++grp) {
            const int o4 = oA + grp * 4;
            const float4 a4 = *(const float4*)(ga + o4);                  // s_load
#pragma unroll
            for (int rr = 0; rr < 8; ++rr) {
                const float4 wi4 = *(const float4*)(gwi + rr * DOUT + o4); // s_load
#pragma unroll
                for (int s2 = 0; s2 < 4; ++s2) {
                    const float aq = ((const float*)&a4)[s2];
                    const float wi = ((const float*)&wi4)[s2];
                    ab[rr] = __builtin_fmaf(aq, __builtin_fabsf(wi + bufA[grp * 4 + s2]), ab[rr]);
                }
            }
        }
        if (cc < 3) {
#pragma unroll
            for (int s = 0; s < 16; ++s) bufA[s] = wj[(oA + 32 + s) * Nq];
        }
#pragma unroll
        for (int grp = 0; grp < 4; ++grp) {
            const int o4 = oB + grp * 4;
            const float4 a4 = *(const float4*)(ga + o4);                  // s_load
#pragma unroll
            for (int rr = 0; rr < 8; ++rr) {
                const float4 wi4 = *(const float4*)(gwi + rr * DOUT + o4); // s_load
#pragma unroll
                for (int s2 = 0; s2 < 4; ++s2) {
                    const float aq = ((const float*)&a4)[s2];
                    const float wi = ((const float*)&wi4)[s2];
                    ab[rr] = __builtin_fmaf(aq, __builtin_fabsf(wi + bufB[grp * 4 + s2]), ab[rr]);
                }
            }
        }
    }

    // combine the two o-halves
    __shared__ float sAb[8][512];         // 16 KB
    if (half == 1) {
#pragma unroll
        for (int rr = 0; rr < 8; ++rr) sAb[rr][j] = ab[rr];
    }
    __syncthreads();

    float e[8];
    if (half == 0) {
        const float rj = gr[j];           // coalesced
#pragma unroll
        for (int rr = 0; rr < 8; ++rr) {
            const float abf = ab[rr] + sAb[rr][j];
            e[rr] = 0.6f * (gr[i0 + rr] + rj) + 0.4f * abf;   // gr[i0+rr] s_load
        }
    }

    __shared__ float wred[2][8][8];       // [max/sum][row][wave 0..7]
    const int lane = t & 63;
    const int w    = t >> 6;              // 0..15; half 0 = 0..7

#pragma unroll
    for (int rr = 0; rr < 8; ++rr) {
        float v = (half == 0) ? e[rr] : -1e30f;
#pragma unroll
        for (int off = 32; off > 0; off >>= 1) v = fmaxf(v, __shfl_xor(v, off));
        if (lane == 0 && half == 0) wred[0][rr][w] = v;
    }
    __syncthreads();

    float p[8];
    if (half == 0) {
#pragma unroll
        for (int rr = 0; rr < 8; ++rr) {
            const float4 q0 = *(const float4*)&wred[0][rr][0];
            const float4 q1 = *(const float4*)&wred[0][rr][4];
            const float m = fmaxf(fmaxf(fmaxf(q0.x, q0.y), fmaxf(q0.z, q0.w)),
                                  fmaxf(fmaxf(q1.x, q1.y), fmaxf(q1.z, q1.w)));
            p[rr] = __expf(e[rr] - m);
        }
    }
#pragma unroll
    for (int rr = 0; rr < 8; ++rr) {
        float v = (half == 0) ? p[rr] : 0.f;
#pragma unroll
        for (int off = 32; off > 0; off >>= 1) v += __shfl_xor(v, off);
        if (lane == 0 && half == 0) wred[1][rr][w] = v;
    }
    __syncthreads();

    if (half == 0) {
        float* prow = P + ((size_t)b * Nq + i0) * Nq + j;
#pragma unroll
        for (int rr = 0; rr < 8; ++rr) {
            const float4 q0 = *(const float4*)&wred[1][rr][0];
            const float4 q1 = *(const float4*)&wred[1][rr][4];
            const float s = (q0.x + q0.y + q0.z + q0.w) + (q1.x + q1.y + q1.z + q1.w);
            prow[rr * Nq] = p[rr] * (1.0f / s);   // coalesced
        }
    }
}

// ---------------------------------------------------------------------------
// K3: out = P @ Wh. Mirror of K1: thread = (j-phase, o-quad); each Wh float4
// loaded once, used for all 8 i-rows; P rows s_load; LDS partial reduce.
// ---------------------------------------------------------------------------
__global__ __launch_bounds__(512, 2) void k3_av(const float* __restrict__ Wh,
                                                const float* __restrict__ P,
                                                float* __restrict__ out) {
    const int t   = threadIdx.x;
    const int blk = blockIdx.x;           // 256
    const int b   = blk & 3;
    const int i0  = (blk >> 2) << 3;
    const int p   = __builtin_amdgcn_readfirstlane(t >> 6);  // j-phase 0..7
    const int oq  = t & 63;               // o-quad

    const float* __restrict__ pbase = P + ((size_t)(b * Nq) + i0) * Nq;   // + row*Nq
    const float4* __restrict__ wh4  = (const float4*)(Wh + (size_t)b * Nq * DOUT) + oq;

    float4 acc[8];
#pragma unroll
    for (int rr = 0; rr < 8; ++rr) acc[rr] = make_float4(0.f, 0.f, 0.f, 0.f);

    const int j0 = p * 64;                // this phase's 64-j chunk
    float4 bufA[4], bufB[4];
#pragma unroll
    for (int s = 0; s < 4; ++s) bufA[s] = wh4[(j0 + s) * 64];

    for (int it = 0; it < 8; ++it) {      // 8 j per it
        const int jA = j0 + it * 8, jB = jA + 4;
#pragma unroll
        for (int s = 0; s < 4; ++s) bufB[s] = wh4[(jB + s) * 64];
#pragma unroll
        for (int rr = 0; rr < 8; ++rr) {
            const float4 p4 = *(const float4*)(pbase + rr * Nq + jA);    // s_load
            fma4(acc[rr], p4.x, bufA[0]); fma4(acc[rr], p4.y, bufA[1]);
            fma4(acc[rr], p4.z, bufA[2]); fma4(acc[rr], p4.w, bufA[3]);
        }
        if (it < 7) {
#pragma unroll
            for (int s = 0; s < 4; ++s) bufA[s] = wh4[(jA + 8 + s) * 64];
        }
#pragma unroll
        for (int rr = 0; rr < 8; ++rr) {
            const float4 p4 = *(const float4*)(pbase + rr * Nq + jB);    // s_load
            fma4(acc[rr], p4.x, bufB[0]); fma4(acc[rr], p4.y, bufB[1]);
            fma4(acc[rr], p4.z, bufB[2]); fma4(acc[rr], p4.w, bufB[3]);
        }
    }

    __shared__ float4 sPart[8][8][64];    // [phase][row][oq] = 64 KB
#pragma unroll
    for (int rr = 0; rr < 8; ++rr) sPart[p][rr][oq] = acc[rr];
    __syncthreads();

    const int g = p;
    float4 fin = make_float4(0.f, 0.f, 0.f, 0.f);
#pragma unroll
    for (int pp = 0; pp < 8; ++pp) {
        const float4 v = sPart[pp][g][oq];
        fin.x += v.x; fin.y += v.y; fin.z += v.z; fin.w += v.w;
    }

    ((float4*)(out + ((size_t)(b * Nq) + i0 + g) * DOUT))[oq] = fin;
}

// ---------------------------------------------------------------------------
extern "C" void kernel_launch(void* const* d_in, const int* in_sizes, int n_in,
                              void* d_out, int out_size, void* d_ws, size_t ws_size,
                              hipStream_t stream) {
    const float* H = (const float*)d_in[0];   // [4,512,512]
    const float* W = (const float*)d_in[1];   // [256,512]
    const float* a = (const float*)d_in[2];   // [256,1]
    float* out = (float*)d_out;               // [4,512,256]

    float* Wh  = (float*)d_ws;                 // 2 MB
    float* WhT = Wh  + Bq * Nq * DOUT;         // 2 MB
    float* P   = WhT + Bq * Nq * DOUT;         // 4 MB
    float* WT  = P;                            // 0.5 MB, dead before K2 writes P
    float* r   = out;                          // 8 KB stash in d_out; K2 reads it
                                               // before K3 overwrites all of out

    hipLaunchKernelGGL(k0_wt,   dim3(16, 8), dim3(32, 8), 0, stream, W, WT);
    hipLaunchKernelGGL(k1_wh,   dim3(256),   dim3(512),   0, stream, H, WT, a, Wh, WhT, r);
    hipLaunchKernelGGL(k2_attn, dim3(256),   dim3(1024),  0, stream, Wh, WhT, a, r, P);
    hipLaunchKernelGGL(k3_av,   dim3(256),   dim3(512),   0, stream, Wh, P, out);
}